// Round 2
// baseline (248.606 us; speedup 1.0000x reference)
//
#include <hip/hip_runtime.h>

#define NDIM 2048
#define FDIM 64
#define KDIM 8
#define BDIM 32
#define TILE 64
#define PAD  4   // row stride 68 floats: bank step 4/row -> <=2-way conflicts

// ---------------------------------------------------------------------------
// Fused: for each 64x64 (n,m) tile, accumulate cov_k fragments for all 8 k in
// registers (acc[8][4][4], statically indexed), fold sr^2 into the diagonal,
// then mix with p[b,:] and stream all 32 output planes. No intermediate HBM
// traffic; output written exactly once. d_out never read.
//
// Mapping: rows  gn = n0 + ty + 16*i  (ty = t>>4, i = 0..3)
//          cols  gm = m0 + tx + 16*j  (tx = t&15, j = 0..3)
// LDS reads: a-frag broadcast (addr depends on ty only, banks 4*ty distinct);
// b-frag lanes tx at bank 4*tx -> 2-way (free). Stores scalar but each wave
// covers 4 rows x 64B contiguous segments.
// ---------------------------------------------------------------------------
__global__ __launch_bounds__(256) void rfm_fused_kernel(
    const float* __restrict__ p, const float* __restrict__ L,
    const float* __restrict__ sr, float* __restrict__ out)
{
    __shared__ float An[TILE][FDIM + PAD];
    __shared__ float Am[TILE][FDIM + PAD];

    const int n0 = blockIdx.y * TILE;
    const int m0 = blockIdx.x * TILE;
    const int t  = threadIdx.x;
    const int tx = t & 15;
    const int ty = t >> 4;

    float acc[KDIM][4][4];
    #pragma unroll
    for (int k = 0; k < KDIM; ++k)
        #pragma unroll
        for (int i = 0; i < 4; ++i)
            #pragma unroll
            for (int j = 0; j < 4; ++j) acc[k][i][j] = 0.0f;

    #pragma unroll
    for (int k = 0; k < KDIM; ++k) {
        const float* Lk = L + (size_t)k * (NDIM * FDIM);

        // Stage panels: 64 rows x 64 f = 1024 float4 each; 4 per thread/panel.
        #pragma unroll
        for (int r = 0; r < 4; ++r) {
            const int idx = t + r * 256;
            const int row = idx >> 4;          // 16 float4 per row
            const int fc  = (idx & 15) << 2;
            *(float4*)&An[row][fc] =
                *(const float4*)&Lk[(size_t)(n0 + row) * FDIM + fc];
            *(float4*)&Am[row][fc] =
                *(const float4*)&Lk[(size_t)(m0 + row) * FDIM + fc];
        }
        __syncthreads();

        #pragma unroll 2
        for (int f = 0; f < FDIM; f += 4) {
            float4 a[4], b4[4];
            #pragma unroll
            for (int i = 0; i < 4; ++i)
                a[i] = *(const float4*)&An[ty + 16 * i][f];
            #pragma unroll
            for (int j = 0; j < 4; ++j)
                b4[j] = *(const float4*)&Am[tx + 16 * j][f];
            #pragma unroll
            for (int i = 0; i < 4; ++i)
                #pragma unroll
                for (int j = 0; j < 4; ++j)
                    acc[k][i][j] += a[i].x * b4[j].x + a[i].y * b4[j].y
                                  + a[i].z * b4[j].z + a[i].w * b4[j].w;
        }

        // Diagonal: gn == gm  <=>  n0 == m0 && tx == ty && i == j.
        if (n0 == m0 && tx == ty) {
            #pragma unroll
            for (int i = 0; i < 4; ++i) {
                const float q = sr[k * NDIM + n0 + ty + 16 * i];
                acc[k][i][i] += q * q;
            }
        }
        __syncthreads();   // before next k overwrites the panels
    }

    // Epilogue: out[b] tile = sum_k p[b,k] * acc[k].  b-loop rolled to keep
    // code size in I-cache; p reads are wave-uniform -> scalar loads.
    const size_t NN = (size_t)NDIM * NDIM;
    float* outp = out + (size_t)(n0 + ty) * NDIM + (m0 + tx);
    #pragma unroll 1
    for (int b = 0; b < BDIM; ++b) {
        float pb[KDIM];
        #pragma unroll
        for (int k = 0; k < KDIM; ++k) pb[k] = p[b * KDIM + k];
        float* ob = outp + (size_t)b * NN;
        #pragma unroll
        for (int i = 0; i < 4; ++i) {
            #pragma unroll
            for (int j = 0; j < 4; ++j) {
                float v = 0.0f;
                #pragma unroll
                for (int k = 0; k < KDIM; ++k) v += pb[k] * acc[k][i][j];
                ob[(size_t)(16 * i) * NDIM + 16 * j] = v;
            }
        }
    }
}

extern "C" void kernel_launch(void* const* d_in, const int* in_sizes, int n_in,
                              void* d_out, int out_size, void* d_ws, size_t ws_size,
                              hipStream_t stream)
{
    const float* p  = (const float*)d_in[0];   // (B,K) = (32,8)
    const float* L  = (const float*)d_in[1];   // (K,N,F) = (8,2048,64)
    const float* sr = (const float*)d_in[2];   // (K,N)   = (8,2048)
    float* out = (float*)d_out;                // (B,N,N) = (32,2048,2048)

    dim3 grid(NDIM / TILE, NDIM / TILE);       // 32 x 32 = 1024 blocks
    hipLaunchKernelGGL(rfm_fused_kernel, grid, dim3(256), 0, stream,
                       p, L, sr, out);
}

// Round 3
// 245.034 us; speedup vs baseline: 1.0146x; 1.0146x over previous
//
#include <hip/hip_runtime.h>

#define NDIM 2048
#define FDIM 64
#define KDIM 8
#define BDIM 32
#define TILE 64
#define PAD  4   // row stride 68 floats: bank step 4/row -> <=2-way conflicts

// ---------------------------------------------------------------------------
// Fused: for each 64x64 (n,m) tile, accumulate cov_k fragments for all 8 k in
// registers (acc[8][4][4], statically indexed -> k-loop must stay unrolled),
// fold sr^2 into the diagonal, then mix with p[b,:] (staged in LDS) and
// stream all 32 output planes. Output written exactly once; d_out never read.
//
// R3 change vs R2: f-loop rolled (unroll 1) so total code ~1.4K insts (~11KB)
// fits the 32KB L1I (R2 was ~90KB -> I-fetch stalls); p staged in LDS once
// instead of 8 global loads per epilogue iteration.
//
// Mapping: rows  gn = n0 + ty + 16*i, cols gm = m0 + tx + 16*j.
// LDS reads: a-frag broadcast (4 addrs/wave); b-frag 16 addrs, 2-way (free).
// ---------------------------------------------------------------------------
__global__ __launch_bounds__(256) void rfm_fused_kernel(
    const float* __restrict__ p, const float* __restrict__ L,
    const float* __restrict__ sr, float* __restrict__ out)
{
    __shared__ float An[TILE][FDIM + PAD];
    __shared__ float Am[TILE][FDIM + PAD];
    __shared__ float pl[BDIM * KDIM];   // 256 == blockDim

    const int n0 = blockIdx.y * TILE;
    const int m0 = blockIdx.x * TILE;
    const int t  = threadIdx.x;
    const int tx = t & 15;
    const int ty = t >> 4;

    pl[t] = p[t];   // covered by the first __syncthreads below

    float acc[KDIM][4][4];
    #pragma unroll
    for (int k = 0; k < KDIM; ++k)
        #pragma unroll
        for (int i = 0; i < 4; ++i)
            #pragma unroll
            for (int j = 0; j < 4; ++j) acc[k][i][j] = 0.0f;

    #pragma unroll
    for (int k = 0; k < KDIM; ++k) {
        const float* Lk = L + (size_t)k * (NDIM * FDIM);

        // Stage panels: 64 rows x 64 f = 1024 float4 each; 4 per thread/panel.
        #pragma unroll
        for (int r = 0; r < 4; ++r) {
            const int idx = t + r * 256;
            const int row = idx >> 4;          // 16 float4 per row
            const int fc  = (idx & 15) << 2;
            *(float4*)&An[row][fc] =
                *(const float4*)&Lk[(size_t)(n0 + row) * FDIM + fc];
            *(float4*)&Am[row][fc] =
                *(const float4*)&Lk[(size_t)(m0 + row) * FDIM + fc];
        }
        __syncthreads();

        #pragma unroll 1
        for (int f = 0; f < FDIM; f += 4) {
            float4 a[4], b4[4];
            #pragma unroll
            for (int i = 0; i < 4; ++i)
                a[i] = *(const float4*)&An[ty + 16 * i][f];
            #pragma unroll
            for (int j = 0; j < 4; ++j)
                b4[j] = *(const float4*)&Am[tx + 16 * j][f];
            #pragma unroll
            for (int i = 0; i < 4; ++i)
                #pragma unroll
                for (int j = 0; j < 4; ++j)
                    acc[k][i][j] += a[i].x * b4[j].x + a[i].y * b4[j].y
                                  + a[i].z * b4[j].z + a[i].w * b4[j].w;
        }

        // Diagonal: gn == gm  <=>  n0 == m0 && tx == ty && i == j.
        if (n0 == m0 && tx == ty) {
            #pragma unroll
            for (int i = 0; i < 4; ++i) {
                const float q = sr[k * NDIM + n0 + ty + 16 * i];
                acc[k][i][i] += q * q;
            }
        }
        __syncthreads();   // before next k overwrites the panels
    }

    // Epilogue: out[b] tile = sum_k pl[b,k] * acc[k]. b-loop rolled (I-cache);
    // pl reads are same-address across the wave -> LDS broadcast, ~free.
    const size_t NN = (size_t)NDIM * NDIM;
    float* outp = out + (size_t)(n0 + ty) * NDIM + (m0 + tx);
    #pragma unroll 1
    for (int b = 0; b < BDIM; ++b) {
        float pb[KDIM];
        #pragma unroll
        for (int k = 0; k < KDIM; ++k) pb[k] = pl[b * KDIM + k];
        float* ob = outp + (size_t)b * NN;
        #pragma unroll
        for (int i = 0; i < 4; ++i) {
            #pragma unroll
            for (int j = 0; j < 4; ++j) {
                float v = 0.0f;
                #pragma unroll
                for (int k = 0; k < KDIM; ++k) v += pb[k] * acc[k][i][j];
                ob[(size_t)(16 * i) * NDIM + 16 * j] = v;
            }
        }
    }
}

extern "C" void kernel_launch(void* const* d_in, const int* in_sizes, int n_in,
                              void* d_out, int out_size, void* d_ws, size_t ws_size,
                              hipStream_t stream)
{
    const float* p  = (const float*)d_in[0];   // (B,K) = (32,8)
    const float* L  = (const float*)d_in[1];   // (K,N,F) = (8,2048,64)
    const float* sr = (const float*)d_in[2];   // (K,N)   = (8,2048)
    float* out = (float*)d_out;                // (B,N,N) = (32,2048,2048)

    dim3 grid(NDIM / TILE, NDIM / TILE);       // 32 x 32 = 1024 blocks
    hipLaunchKernelGGL(rfm_fused_kernel, grid, dim3(256), 0, stream,
                       p, L, sr, out);
}

// Round 4
// 181.502 us; speedup vs baseline: 1.3697x; 1.3500x over previous
//
#include <hip/hip_runtime.h>

#define NDIM 2048
#define FDIM 64
#define KDIM 8
#define BDIM 32
#define TILE 64
#define PAD  4               // row stride 68 floats -> <=2-way LDS read conflicts
#define LROW (FDIM + PAD)

// ---------------------------------------------------------------------------
// Fused: per 64x64 (n,m) tile, accumulate cov_k fragments for all 8 k in
// registers (acc[8][4][4], statically indexed), fold sr^2 into the diagonal,
// then mix with p[b,:] and stream all 32 output planes.
//
// R4 change vs R3: epilogue stores are float4 via an LDS transpose. R3 issued
// 512 scalar stores/thread (wave footprint = 4 scattered 64-B segments per
// instr) and ran at an effective 2.2 TB/s write BW. Now: per 2 b-planes,
// scatter mixed values into the dead An/Am panels, barrier, read back as
// rows, store dwordx4 (wave footprint = 4 x 256-B contiguous segments).
// ---------------------------------------------------------------------------
__global__ __launch_bounds__(256) void rfm_fused_kernel(
    const float* __restrict__ p, const float* __restrict__ L,
    const float* __restrict__ sr, float* __restrict__ out)
{
    __shared__ float An[TILE][LROW];
    __shared__ float Am[TILE][LROW];
    __shared__ float pl[BDIM * KDIM];   // 256 == blockDim

    const int n0 = blockIdx.y * TILE;
    const int m0 = blockIdx.x * TILE;
    const int t  = threadIdx.x;
    const int tx = t & 15;
    const int ty = t >> 4;

    pl[t] = p[t];   // covered by the first __syncthreads below

    float acc[KDIM][4][4];
    #pragma unroll
    for (int k = 0; k < KDIM; ++k)
        #pragma unroll
        for (int i = 0; i < 4; ++i)
            #pragma unroll
            for (int j = 0; j < 4; ++j) acc[k][i][j] = 0.0f;

    #pragma unroll
    for (int k = 0; k < KDIM; ++k) {
        const float* Lk = L + (size_t)k * (NDIM * FDIM);

        // Stage panels: 64 rows x 64 f = 1024 float4 each; 4 per thread/panel.
        #pragma unroll
        for (int r = 0; r < 4; ++r) {
            const int idx = t + r * 256;
            const int row = idx >> 4;          // 16 float4 per row
            const int fc  = (idx & 15) << 2;
            *(float4*)&An[row][fc] =
                *(const float4*)&Lk[(size_t)(n0 + row) * FDIM + fc];
            *(float4*)&Am[row][fc] =
                *(const float4*)&Lk[(size_t)(m0 + row) * FDIM + fc];
        }
        __syncthreads();

        #pragma unroll 1
        for (int f = 0; f < FDIM; f += 4) {
            float4 a[4], b4[4];
            #pragma unroll
            for (int i = 0; i < 4; ++i)
                a[i] = *(const float4*)&An[ty + 16 * i][f];
            #pragma unroll
            for (int j = 0; j < 4; ++j)
                b4[j] = *(const float4*)&Am[tx + 16 * j][f];
            #pragma unroll
            for (int i = 0; i < 4; ++i)
                #pragma unroll
                for (int j = 0; j < 4; ++j)
                    acc[k][i][j] += a[i].x * b4[j].x + a[i].y * b4[j].y
                                  + a[i].z * b4[j].z + a[i].w * b4[j].w;
        }

        // Diagonal: gn == gm  <=>  n0 == m0 && tx == ty && i == j.
        if (n0 == m0 && tx == ty) {
            #pragma unroll
            for (int i = 0; i < 4; ++i) {
                const float q = sr[k * NDIM + n0 + ty + 16 * i];
                acc[k][i][i] += q * q;
            }
        }
        __syncthreads();   // panels consumed; safe to overwrite next k (or epilogue)
    }

    // ---- Epilogue: 2 b-planes per pass through the dead An/Am panels ----
    const size_t NN = (size_t)NDIM * NDIM;
    const int c0 = tx << 2;                       // 0..60, float4-aligned col
    float* obase = out + (size_t)n0 * NDIM + m0;

    #pragma unroll 1
    for (int b = 0; b < BDIM; b += 2) {
        float pa[KDIM], pb[KDIM];
        #pragma unroll
        for (int k = 0; k < KDIM; ++k) {
            pa[k] = pl[b * KDIM + k];
            pb[k] = pl[(b + 1) * KDIM + k];
        }
        #pragma unroll
        for (int i = 0; i < 4; ++i) {
            #pragma unroll
            for (int j = 0; j < 4; ++j) {
                float va = 0.0f, vb = 0.0f;
                #pragma unroll
                for (int k = 0; k < KDIM; ++k) {
                    va += pa[k] * acc[k][i][j];
                    vb += pb[k] * acc[k][i][j];
                }
                An[ty + 16 * i][tx + 16 * j] = va;
                Am[ty + 16 * i][tx + 16 * j] = vb;
            }
        }
        __syncthreads();
        #pragma unroll
        for (int q = 0; q < 4; ++q) {
            const int row = ty + 16 * q;          // wave: 4 rows x 256B contiguous
            const float4 wa = *(const float4*)&An[row][c0];
            const float4 wb = *(const float4*)&Am[row][c0];
            float* dst = obase + (size_t)row * NDIM + c0;
            *(float4*)(dst + (size_t)b * NN)       = wa;
            *(float4*)(dst + (size_t)(b + 1) * NN) = wb;
        }
        __syncthreads();   // before next pass overwrites the panels
    }
}

extern "C" void kernel_launch(void* const* d_in, const int* in_sizes, int n_in,
                              void* d_out, int out_size, void* d_ws, size_t ws_size,
                              hipStream_t stream)
{
    const float* p  = (const float*)d_in[0];   // (B,K) = (32,8)
    const float* L  = (const float*)d_in[1];   // (K,N,F) = (8,2048,64)
    const float* sr = (const float*)d_in[2];   // (K,N)   = (8,2048)
    float* out = (float*)d_out;                // (B,N,N) = (32,2048,2048)

    dim3 grid(NDIM / TILE, NDIM / TILE);       // 32 x 32 = 1024 blocks
    hipLaunchKernelGGL(rfm_fused_kernel, grid, dim3(256), 0, stream,
                       p, L, sr, out);
}

// Round 5
// 134.151 us; speedup vs baseline: 1.8532x; 1.3530x over previous
//
#include <hip/hip_runtime.h>

#define NDIM 2048
#define FDIM 64
#define KDIM 8
#define BDIM 32
#define TILE 64
#define BFROW 72   // bf16 elems per panel row (64 + 8 pad): 144-B stride -> bank-balanced
#define FROW  68   // f32 elems per epilogue row (64 + 4 pad)

typedef __attribute__((ext_vector_type(8))) short short8;
typedef __attribute__((ext_vector_type(4))) float f32x4;

static __device__ __forceinline__ unsigned short f2bf(float x) {
    unsigned u = __float_as_uint(x);                 // RNE to bf16
    return (unsigned short)((u + 0x7fffu + ((u >> 16) & 1u)) >> 16);
}

// ---------------------------------------------------------------------------
// Fused, MFMA cov: per 64x64 (n,m) tile, cov_k fragments for all 8 k held in
// MFMA accumulators (acc[8][2][2] f32x4 = 128 VGPR), diagonal sr^2 folded in,
// then mix with p[b,:] and stream 32 planes via the R4 LDS-transpose + float4
// store path. Cov phase: L panels cast to bf16 in LDS, each wave computes one
// 32x32 sub-tile as 2x2 mfma_f32_16x16x32_bf16 tiles (verified m89/m93
// layout: A and B^T both gathered as [row][f], C col=lane&15,
// row=(lane>>4)*4+reg). vs R3/R4 fp32-FMA cov: ~16x less LDS, ~25x less VALU.
// ---------------------------------------------------------------------------
__global__ __launch_bounds__(256, 2) void rfm_fused_mfma(
    const float* __restrict__ p, const float* __restrict__ L,
    const float* __restrict__ sr, float* __restrict__ out)
{
    __shared__ float pl[BDIM * KDIM];
    __shared__ __align__(16) char smem[2 * TILE * FROW * 4];   // 34816 B union

    unsigned short* An = (unsigned short*)smem;        // [TILE][BFROW] bf16
    unsigned short* Am = An + TILE * BFROW;
    float* Pn = (float*)smem;                          // [TILE][FROW] f32 (epilogue)
    float* Pm = Pn + TILE * FROW;

    const int n0 = blockIdx.y * TILE;
    const int m0 = blockIdx.x * TILE;
    const int t  = threadIdx.x;
    const int lane = t & 63;
    const int w   = t >> 6;        // wave 0..3
    const int wr  = w >> 1;        // row 32-block of this wave
    const int wc  = w & 1;         // col 32-block
    const int l15 = lane & 15;
    const int l4  = lane >> 4;     // 0..3

    pl[t] = p[t];                  // covered by first __syncthreads below

    f32x4 acc[KDIM][2][2];
    #pragma unroll
    for (int k = 0; k < KDIM; ++k)
        #pragma unroll
        for (int ti = 0; ti < 2; ++ti)
            #pragma unroll
            for (int tj = 0; tj < 2; ++tj)
                acc[k][ti][tj] = (f32x4){0.f, 0.f, 0.f, 0.f};

    #pragma unroll
    for (int k = 0; k < KDIM; ++k) {
        const float* Lk = L + (size_t)k * (NDIM * FDIM);

        // Stage panels as bf16: 64 rows x 64 f each; coalesced float4 reads.
        #pragma unroll
        for (int r = 0; r < 4; ++r) {
            const int idx = t + r * 256;
            const int row = idx >> 4;          // 16 float4 per row
            const int fc  = (idx & 15) << 2;
            const float4 va = *(const float4*)&Lk[(size_t)(n0 + row) * FDIM + fc];
            const float4 vb = *(const float4*)&Lk[(size_t)(m0 + row) * FDIM + fc];
            ushort4 ua, ub;
            ua.x = f2bf(va.x); ua.y = f2bf(va.y); ua.z = f2bf(va.z); ua.w = f2bf(va.w);
            ub.x = f2bf(vb.x); ub.y = f2bf(vb.y); ub.z = f2bf(vb.z); ub.w = f2bf(vb.w);
            *(ushort4*)&An[row * BFROW + fc] = ua;
            *(ushort4*)&Am[row * BFROW + fc] = ub;
        }
        __syncthreads();

        // Fragments: lane l -> row (l&15), f = s*32 + (l>>4)*8 .. +7
        short8 af[2][2], bv[2][2];
        #pragma unroll
        for (int ti = 0; ti < 2; ++ti)
            #pragma unroll
            for (int s = 0; s < 2; ++s) {
                af[ti][s] = *(const short8*)
                    &An[(wr * 32 + ti * 16 + l15) * BFROW + s * 32 + l4 * 8];
                bv[ti][s] = *(const short8*)
                    &Am[(wc * 32 + ti * 16 + l15) * BFROW + s * 32 + l4 * 8];
            }
        #pragma unroll
        for (int ti = 0; ti < 2; ++ti)
            #pragma unroll
            for (int tj = 0; tj < 2; ++tj)
                #pragma unroll
                for (int s = 0; s < 2; ++s)
                    acc[k][ti][tj] = __builtin_amdgcn_mfma_f32_16x16x32_bf16(
                        af[ti][s], bv[tj][s], acc[k][ti][tj], 0, 0, 0);
        __syncthreads();   // panels consumed; next k (or epilogue) may overwrite
    }

    // Diagonal: gn == gm. C/D map: row = l4*4 + reg, col = l15 (within 16x16).
    if (n0 == m0 && wr == wc) {
        #pragma unroll
        for (int k = 0; k < KDIM; ++k)
            #pragma unroll
            for (int ti = 0; ti < 2; ++ti)
                #pragma unroll
                for (int reg = 0; reg < 4; ++reg) {
                    const int row = l4 * 4 + reg;
                    if (row == l15) {
                        const float q = sr[k * NDIM + n0 + wr * 32 + ti * 16 + row];
                        acc[k][ti][ti][reg] += q * q;
                    }
                }
    }

    // ---- Epilogue: 2 b-planes per pass; scatter (MFMA layout) -> LDS,
    //      read back rows, float4 stores (4 x 256-B segments per wave-inst).
    const size_t NN = (size_t)NDIM * NDIM;
    const int tx = t & 15;
    const int ty = t >> 4;
    float* obase = out + (size_t)n0 * NDIM + m0;

    #pragma unroll 1
    for (int b = 0; b < BDIM; b += 2) {
        float pa[KDIM], pb[KDIM];
        #pragma unroll
        for (int k = 0; k < KDIM; ++k) {
            pa[k] = pl[b * KDIM + k];
            pb[k] = pl[(b + 1) * KDIM + k];
        }
        #pragma unroll
        for (int ti = 0; ti < 2; ++ti)
            #pragma unroll
            for (int tj = 0; tj < 2; ++tj)
                #pragma unroll
                for (int reg = 0; reg < 4; ++reg) {
                    const int rl = wr * 32 + ti * 16 + l4 * 4 + reg;
                    const int cl = wc * 32 + tj * 16 + l15;
                    float va = 0.f, vb = 0.f;
                    #pragma unroll
                    for (int k = 0; k < KDIM; ++k) {
                        va += pa[k] * acc[k][ti][tj][reg];
                        vb += pb[k] * acc[k][ti][tj][reg];
                    }
                    Pn[rl * FROW + cl] = va;
                    Pm[rl * FROW + cl] = vb;
                }
        __syncthreads();
        #pragma unroll
        for (int q = 0; q < 4; ++q) {
            const int row = ty + 16 * q;
            const f32x4 wa = *(const f32x4*)&Pn[row * FROW + tx * 4];
            const f32x4 wb = *(const f32x4*)&Pm[row * FROW + tx * 4];
            float* dst = obase + (size_t)row * NDIM + tx * 4;
            *(f32x4*)(dst + (size_t)b * NN)       = wa;
            *(f32x4*)(dst + (size_t)(b + 1) * NN) = wb;
        }
        __syncthreads();   // before next pass overwrites the planes
    }
}

extern "C" void kernel_launch(void* const* d_in, const int* in_sizes, int n_in,
                              void* d_out, int out_size, void* d_ws, size_t ws_size,
                              hipStream_t stream)
{
    const float* p  = (const float*)d_in[0];   // (B,K) = (32,8)
    const float* L  = (const float*)d_in[1];   // (K,N,F) = (8,2048,64)
    const float* sr = (const float*)d_in[2];   // (K,N)   = (8,2048)
    float* out = (float*)d_out;                // (B,N,N) = (32,2048,2048)

    dim3 grid(NDIM / TILE, NDIM / TILE);       // 32 x 32 = 1024 blocks
    hipLaunchKernelGGL(rfm_fused_mfma, grid, dim3(256), 0, stream,
                       p, L, sr, out);
}

// Round 8
// 125.585 us; speedup vs baseline: 1.9796x; 1.0682x over previous
//
#include <hip/hip_runtime.h>

#define NDIM 2048
#define FDIM 64
#define KDIM 8
#define BDIM 32
#define TILE 64
#define BFROW 72   // bf16 elems per panel row (64 + 8 pad)
#define FROW  68   // f32 elems per transpose-panel row (64 + 4 pad)

typedef __attribute__((ext_vector_type(8))) short short8;
typedef __attribute__((ext_vector_type(4))) float f32x4;

static __device__ __forceinline__ unsigned short f2bf(float x) {
    unsigned u = __float_as_uint(x);                 // RNE to bf16
    return (unsigned short)((u + 0x7fffu + ((u >> 16) & 1u)) >> 16);
}

// ---------------------------------------------------------------------------
// R8 = R5's exact passing cov phase + R5's mix-then-scatter epilogue, with:
//  (a) 4 output planes per pass (4 LDS panels, 69.6 KB, 2 blocks/CU) ->
//      8 passes instead of 16;
//  (b) epilogue barriers are lgkmcnt(0)-only + raw s_barrier: global stores
//      are never drained at a barrier (no vmcnt(0)), so the write pipe
//      streams continuously; LDS ordering (scatter-writes before readback-
//      reads, reads before next overwrite) is fully covered by lgkmcnt.
// No acc+covr dual-array structure (suspected miscompile in R6/R7).
// ---------------------------------------------------------------------------
__global__ __launch_bounds__(256, 2) void rfm_fused_mfma(
    const float* __restrict__ p, const float* __restrict__ L,
    const float* __restrict__ sr, float* __restrict__ out)
{
    __shared__ float pl[BDIM * KDIM];
    __shared__ __align__(16) char smem[4 * TILE * FROW * 4];   // 69632 B

    unsigned short* An = (unsigned short*)smem;        // [TILE][BFROW] bf16 (cov)
    unsigned short* Am = An + TILE * BFROW;

    const int n0 = blockIdx.y * TILE;
    const int m0 = blockIdx.x * TILE;
    const int t  = threadIdx.x;
    const int lane = t & 63;
    const int w   = t >> 6;        // wave 0..3
    const int wr  = w >> 1;        // row 32-block
    const int wc  = w & 1;         // col 32-block
    const int l15 = lane & 15;
    const int l4  = lane >> 4;     // 0..3

    pl[t] = p[t];                  // covered by first __syncthreads below

    f32x4 acc[KDIM][2][2];
    #pragma unroll
    for (int k = 0; k < KDIM; ++k)
        #pragma unroll
        for (int ti = 0; ti < 2; ++ti)
            #pragma unroll
            for (int tj = 0; tj < 2; ++tj)
                acc[k][ti][tj] = (f32x4){0.f, 0.f, 0.f, 0.f};

    // ---- 1) cov phase (VERBATIM from passing R5) ----
    #pragma unroll
    for (int k = 0; k < KDIM; ++k) {
        const float* Lk = L + (size_t)k * (NDIM * FDIM);

        #pragma unroll
        for (int r = 0; r < 4; ++r) {
            const int idx = t + r * 256;
            const int row = idx >> 4;          // 16 float4 per row
            const int fc  = (idx & 15) << 2;
            const float4 va = *(const float4*)&Lk[(size_t)(n0 + row) * FDIM + fc];
            const float4 vb = *(const float4*)&Lk[(size_t)(m0 + row) * FDIM + fc];
            ushort4 ua, ub;
            ua.x = f2bf(va.x); ua.y = f2bf(va.y); ua.z = f2bf(va.z); ua.w = f2bf(va.w);
            ub.x = f2bf(vb.x); ub.y = f2bf(vb.y); ub.z = f2bf(vb.z); ub.w = f2bf(vb.w);
            *(ushort4*)&An[row * BFROW + fc] = ua;
            *(ushort4*)&Am[row * BFROW + fc] = ub;
        }
        __syncthreads();

        short8 af[2][2], bv[2][2];
        #pragma unroll
        for (int ti = 0; ti < 2; ++ti)
            #pragma unroll
            for (int s = 0; s < 2; ++s) {
                af[ti][s] = *(const short8*)
                    &An[(wr * 32 + ti * 16 + l15) * BFROW + s * 32 + l4 * 8];
                bv[ti][s] = *(const short8*)
                    &Am[(wc * 32 + ti * 16 + l15) * BFROW + s * 32 + l4 * 8];
            }
        #pragma unroll
        for (int ti = 0; ti < 2; ++ti)
            #pragma unroll
            for (int tj = 0; tj < 2; ++tj)
                #pragma unroll
                for (int s = 0; s < 2; ++s)
                    acc[k][ti][tj] = __builtin_amdgcn_mfma_f32_16x16x32_bf16(
                        af[ti][s], bv[tj][s], acc[k][ti][tj], 0, 0, 0);
        __syncthreads();   // panels consumed; next k (or epilogue) may overwrite
    }

    // Diagonal: C/D map row = l4*4 + reg, col = l15 (within 16x16 tile).
    if (n0 == m0 && wr == wc) {
        #pragma unroll
        for (int k = 0; k < KDIM; ++k)
            #pragma unroll
            for (int ti = 0; ti < 2; ++ti)
                #pragma unroll
                for (int reg = 0; reg < 4; ++reg) {
                    const int row = l4 * 4 + reg;
                    if (row == l15) {
                        const float q = sr[k * NDIM + n0 + wr * 32 + ti * 16 + row];
                        acc[k][ti][ti][reg] += q * q;
                    }
                }
    }

    // ---- 2) epilogue: 4 planes/pass, mix -> scatter -> wide stores ----
    float* const P0 = (float*)smem;
    float* const P1 = (float*)(smem + 1 * TILE * FROW * 4);
    float* const P2 = (float*)(smem + 2 * TILE * FROW * 4);
    float* const P3 = (float*)(smem + 3 * TILE * FROW * 4);
    float* const Pp[4] = { P0, P1, P2, P3 };

    const int tx = t & 15;
    const int ty = t >> 4;
    const size_t NN = (size_t)NDIM * NDIM;
    float* obase = out + (size_t)n0 * NDIM + m0;

    #pragma unroll 1
    for (int b = 0; b < BDIM; b += 4) {
        float pv[4][KDIM];
        #pragma unroll
        for (int u = 0; u < 4; ++u)
            #pragma unroll
            for (int k = 0; k < KDIM; ++k)
                pv[u][k] = pl[(b + u) * KDIM + k];

        // mix + scatter (MFMA layout -> row-major panels)
        #pragma unroll
        for (int ti = 0; ti < 2; ++ti)
            #pragma unroll
            for (int tj = 0; tj < 2; ++tj)
                #pragma unroll
                for (int reg = 0; reg < 4; ++reg) {
                    const int rl = wr * 32 + ti * 16 + l4 * 4 + reg;
                    const int cl = wc * 32 + tj * 16 + l15;
                    #pragma unroll
                    for (int u = 0; u < 4; ++u) {
                        float v = 0.0f;
                        #pragma unroll
                        for (int k = 0; k < KDIM; ++k)
                            v += pv[u][k] * acc[k][ti][tj][reg];
                        Pp[u][rl * FROW + cl] = v;
                    }
                }
        asm volatile("s_waitcnt lgkmcnt(0)" ::: "memory");  // my ds_writes done
        __builtin_amdgcn_s_barrier();                        // all writes done
        __builtin_amdgcn_sched_barrier(0);

        // readback rows + wide stores (4 x 256-B segments per wave-inst);
        // stores stay in flight across the next barrier (no vmcnt wait).
        #pragma unroll
        for (int q = 0; q < 4; ++q) {
            const int row = ty + 16 * q;
            #pragma unroll
            for (int u = 0; u < 4; ++u) {
                const f32x4 wv = *(const f32x4*)&Pp[u][row * FROW + tx * 4];
                *(f32x4*)(obase + (size_t)(b + u) * NN
                                + (size_t)row * NDIM + tx * 4) = wv;
            }
        }
        asm volatile("s_waitcnt lgkmcnt(0)" ::: "memory");  // my ds_reads done
        __builtin_amdgcn_s_barrier();                        // safe to overwrite
        __builtin_amdgcn_sched_barrier(0);
    }
}

extern "C" void kernel_launch(void* const* d_in, const int* in_sizes, int n_in,
                              void* d_out, int out_size, void* d_ws, size_t ws_size,
                              hipStream_t stream)
{
    const float* p  = (const float*)d_in[0];   // (B,K) = (32,8)
    const float* L  = (const float*)d_in[1];   // (K,N,F) = (8,2048,64)
    const float* sr = (const float*)d_in[2];   // (K,N)   = (8,2048)
    float* out = (float*)d_out;                // (B,N,N) = (32,2048,2048)

    dim3 grid(NDIM / TILE, NDIM / TILE);       // 32 x 32 = 1024 blocks
    hipLaunchKernelGGL(rfm_fused_mfma, grid, dim3(256), 0, stream,
                       p, L, sr, out);
}